// Round 5
// baseline (625.641 us; speedup 1.0000x reference)
//
#include <hip/hip_runtime.h>

#define N_NODES    100000
#define N_EDGES    1600000
#define D_FEAT     64
#define N_GRAPHS   1000
#define D_MSG      30
#define D_H1       20
#define D_H2       10
#define P_STRIDE   64     // P row: [0..29]=P0(src proj + bias), pad, [32..61]=P1(dst proj), pad
#define N_SCAN     (N_NODES + 1)
#define N_SCAN_PAD 100004
#define NB_SCAN    ((N_SCAN + 1023) / 1024)   // 98
#define NB_EDGE    (N_EDGES / 256)            // 6250
#define NB_NODE    ((N_NODES + 255) / 256)    // 391

// ---------------------------------------------------------------------------
// K0: merged  (a) histogram of dst over all 6250 blocks
//             (b) per-node projections P0/P1 on the first 391 blocks
// W0|W1 (rows 0..127 of W_msg) staged in LDS stride-32 -> uniform broadcasts.
// ---------------------------------------------------------------------------
__global__ __launch_bounds__(256, 4) void node_proj_hist_kernel(
    const int*   __restrict__ edge_index,  // [2][N_EDGES]
    const float* __restrict__ node_attr,   // [N_NODES][64]
    const float* __restrict__ W_msg,       // [192][30]
    const float* __restrict__ b_msg,       // [30]
    float*       __restrict__ P,           // [N_NODES][P_STRIDE]
    int*         __restrict__ cnt)         // [N_NODES] (pre-zeroed)
{
    const int t   = threadIdx.x;
    const int bid = blockIdx.x;

    // (a) histogram: every block covers 256 edges
    {
        const int e = bid * 256 + t;
        atomicAdd(&cnt[edge_index[N_EDGES + e]], 1);
    }

    if (bid >= NB_NODE) return;

    // (b) node projection
    __shared__ float wlds[128 * 32];
#pragma unroll
    for (int i = 0; i < 16; ++i) {
        const int f = t + i * 256;          // 0..4095
        const int k = f >> 5, j = f & 31;
        wlds[f] = (j < D_MSG) ? W_msg[k * D_MSG + j] : 0.0f;
    }
    __syncthreads();

    const int n = bid * 256 + t;
    if (n >= N_NODES) return;

    float a0[32], a1[32];
#pragma unroll
    for (int j = 0; j < 32; ++j) { a0[j] = 0.0f; a1[j] = 0.0f; }

    const float4* px = (const float4*)(node_attr + (size_t)n * D_FEAT);
#pragma unroll 4
    for (int q = 0; q < 16; ++q) {
        const float4 v = px[q];
        const float ev[4] = { v.x, v.y, v.z, v.w };
#pragma unroll
        for (int r = 0; r < 4; ++r) {
            const int k = 4 * q + r;
            const float4* w0 = (const float4*)&wlds[k * 32];
            const float4* w1 = (const float4*)&wlds[(64 + k) * 32];
#pragma unroll
            for (int jq = 0; jq < 8; ++jq) {
                const float4 w0v = w0[jq];
                const float4 w1v = w1[jq];
                a0[4*jq+0] = fmaf(ev[r], w0v.x, a0[4*jq+0]);
                a0[4*jq+1] = fmaf(ev[r], w0v.y, a0[4*jq+1]);
                a0[4*jq+2] = fmaf(ev[r], w0v.z, a0[4*jq+2]);
                a0[4*jq+3] = fmaf(ev[r], w0v.w, a0[4*jq+3]);
                a1[4*jq+0] = fmaf(ev[r], w1v.x, a1[4*jq+0]);
                a1[4*jq+1] = fmaf(ev[r], w1v.y, a1[4*jq+1]);
                a1[4*jq+2] = fmaf(ev[r], w1v.z, a1[4*jq+2]);
                a1[4*jq+3] = fmaf(ev[r], w1v.w, a1[4*jq+3]);
            }
        }
    }

    float4* pr = (float4*)(P + (size_t)n * P_STRIDE);
#pragma unroll
    for (int q = 0; q < 7; ++q)
        pr[q] = make_float4(a0[4*q] + b_msg[4*q], a0[4*q+1] + b_msg[4*q+1],
                            a0[4*q+2] + b_msg[4*q+2], a0[4*q+3] + b_msg[4*q+3]);
    pr[7] = make_float4(a0[28] + b_msg[28], a0[29] + b_msg[29], 0.0f, 0.0f);
#pragma unroll
    for (int q = 0; q < 7; ++q)
        pr[8 + q] = make_float4(a1[4*q], a1[4*q+1], a1[4*q+2], a1[4*q+3]);
    pr[15] = make_float4(a1[28], a1[29], 0.0f, 0.0f);
}

// ---------------------------------------------------------------------------
// CSR scan: 2-level exclusive scan of cnt -> offs, cursor init.
// ---------------------------------------------------------------------------
__global__ __launch_bounds__(1024) void scan_a(
    const int* __restrict__ cnt, int* __restrict__ offs, int* __restrict__ bsum)
{
    __shared__ int sh[1024];
    const int t = threadIdx.x;
    const int i = blockIdx.x * 1024 + t;
    const int v = (i < N_SCAN) ? cnt[i] : 0;
    sh[t] = v;
    __syncthreads();
#pragma unroll
    for (int off = 1; off < 1024; off <<= 1) {
        int u = 0;
        if (t >= off) u = sh[t - off];
        __syncthreads();
        if (t >= off) sh[t] += u;
        __syncthreads();
    }
    if (i < N_SCAN) offs[i] = sh[t] - v;
    if (t == 1023) bsum[blockIdx.x] = sh[1023];
}

__global__ __launch_bounds__(128) void scan_b(int* __restrict__ bsum)
{
    __shared__ int sh[128];
    const int t = threadIdx.x;
    const int v = (t < NB_SCAN) ? bsum[t] : 0;
    sh[t] = v;
    __syncthreads();
#pragma unroll
    for (int off = 1; off < 128; off <<= 1) {
        int u = 0;
        if (t >= off) u = sh[t - off];
        __syncthreads();
        if (t >= off) sh[t] += u;
        __syncthreads();
    }
    if (t < NB_SCAN) bsum[t] = sh[t] - v;
}

__global__ __launch_bounds__(1024) void scan_c(
    int* __restrict__ offs, const int* __restrict__ bsum, int* __restrict__ cur)
{
    const int i = blockIdx.x * 1024 + threadIdx.x;
    if (i < N_SCAN) {
        const int o = offs[i] + bsum[blockIdx.x];
        offs[i] = o;
        cur[i]  = o;
    }
}

// ---------------------------------------------------------------------------
// K4: scatter slot records (edge_id, src) into dst-sorted CSR order. 8B/edge.
// ---------------------------------------------------------------------------
__global__ __launch_bounds__(256) void scatter_rec(
    const int* __restrict__ edge_index, int* __restrict__ cur,
    int2* __restrict__ rec)
{
    const int e = blockIdx.x * 256 + threadIdx.x;
    const int s = edge_index[e];
    const int d = edge_index[N_EDGES + e];
    const int p = atomicAdd(&cur[d], 1);
    rec[p] = make_int2(e, s);
}

// ---------------------------------------------------------------------------
// K5: FUSED per-node kernel. 8 lanes per node (8 nodes/wave, 32 nodes/block).
//   m = P0[src] + P1[n] + e_attr[e] @ W2 ; acc += relu(m)   (registers only)
// 3-step shfl_xor butterfly -> node sum on all 8 lanes -> 30->20 head ->
// skip-guarded atomic pool into g. rec[] for the next slot is prefetched
// before the current slot's compute to overlap the index fetch.
// __launch_bounds__(256,8): VGPR cap 64 (measured fit), 32 waves/CU.
// ---------------------------------------------------------------------------
__global__ __launch_bounds__(256, 8) void fused_edge_reduce_head(
    const int2*  __restrict__ rec,         // [N_EDGES] (e, src) dst-sorted
    const int*   __restrict__ offs,        // [N_NODES+1]
    const float* __restrict__ P,           // [N_NODES][P_STRIDE]
    const float* __restrict__ edge_attr,   // [N_EDGES][64]
    const float* __restrict__ W_msg,       // rows 128..191 = W2
    const int*   __restrict__ batch,       // [N_NODES]
    const float* __restrict__ W1,          // [30][20]
    const float* __restrict__ b1,          // [20]
    float*       __restrict__ g)           // [N_GRAPHS][20] (pre-zeroed)
{
    __shared__ float wlds[64 * 32];
    const int t = threadIdx.x;
#pragma unroll
    for (int i = 0; i < 8; ++i) {
        const int f = t + i * 256;          // 0..2047
        const int k = f >> 5, j = f & 31;
        wlds[f] = (j < D_MSG) ? W_msg[(2 * D_FEAT + k) * D_MSG + j] : 0.0f;
    }
    __syncthreads();

    const int lane = t & 63;
    const int l8   = lane & 7;
    const int grp  = lane >> 3;                       // 0..7
    const int wid  = t >> 6;                          // 0..3
    const int n    = blockIdx.x * 32 + wid * 8 + grp; // grid covers exactly N_NODES

    const int o0 = offs[n], o1 = offs[n + 1];
    const float4* p1 = (const float4*)(P + (size_t)n * P_STRIDE + 32);

    float acc[30];
#pragma unroll
    for (int j = 0; j < 30; ++j) acc[j] = 0.0f;

    int  o = o0 + l8;
    int2 r = (o < o1) ? rec[o] : make_int2(0, 0);
    while (o < o1) {
        const int e = r.x, s = r.y;
        const int on = o + 8;
        if (on < o1) r = rec[on];          // prefetch next slot record

        const float4* p0 = (const float4*)(P + (size_t)s * P_STRIDE);
        const float4* pe = (const float4*)(edge_attr + (size_t)e * D_FEAT);

        float m[32];
#pragma unroll
        for (int q = 0; q < 8; ++q) {
            const float4 u = p0[q];
            const float4 w = p1[q];
            m[4*q+0] = u.x + w.x; m[4*q+1] = u.y + w.y;
            m[4*q+2] = u.z + w.z; m[4*q+3] = u.w + w.w;
        }
#pragma unroll 4
        for (int q = 0; q < 16; ++q) {
            const float4 v = pe[q];
            const float ev[4] = { v.x, v.y, v.z, v.w };
#pragma unroll
            for (int rr = 0; rr < 4; ++rr) {
                const float4* wr = (const float4*)&wlds[(4 * q + rr) * 32];
#pragma unroll
                for (int jq = 0; jq < 8; ++jq) {
                    const float4 wv = wr[jq];
                    m[4*jq+0] = fmaf(ev[rr], wv.x, m[4*jq+0]);
                    m[4*jq+1] = fmaf(ev[rr], wv.y, m[4*jq+1]);
                    m[4*jq+2] = fmaf(ev[rr], wv.z, m[4*jq+2]);
                    m[4*jq+3] = fmaf(ev[rr], wv.w, m[4*jq+3]);
                }
            }
        }
#pragma unroll
        for (int j = 0; j < 30; ++j) acc[j] += fmaxf(m[j], 0.0f);
        o = on;
    }

    // 8-lane butterfly: all 8 lanes of the group end with the full node sum
#pragma unroll
    for (int off = 1; off < 8; off <<= 1) {
#pragma unroll
        for (int j = 0; j < 30; ++j)
            acc[j] += __shfl_xor(acc[j], off, 8);
    }

    // head: columns l8, l8+8 on each lane; columns 16..19 on lanes 0..3
    const int gi = batch[n];
    {
        float h = b1[l8];
#pragma unroll
        for (int j = 0; j < 30; ++j) h = fmaf(acc[j], W1[j * D_H1 + l8], h);
        h = fmaxf(h, 0.0f);
        if (h > 0.0f) atomicAdd(&g[(size_t)gi * D_H1 + l8], h);
    }
    {
        const int c = 8 + l8;
        float h = b1[c];
#pragma unroll
        for (int j = 0; j < 30; ++j) h = fmaf(acc[j], W1[j * D_H1 + c], h);
        h = fmaxf(h, 0.0f);
        if (h > 0.0f) atomicAdd(&g[(size_t)gi * D_H1 + c], h);
    }
    if (l8 < 4) {
        const int c = 16 + l8;
        float h = b1[c];
#pragma unroll
        for (int j = 0; j < 30; ++j) h = fmaf(acc[j], W1[j * D_H1 + c], h);
        h = fmaxf(h, 0.0f);
        if (h > 0.0f) atomicAdd(&g[(size_t)gi * D_H1 + c], h);
    }
}

// ---------------------------------------------------------------------------
// K6: per-graph head  out = relu(g @ W2 + b2) @ W3 + b3
// ---------------------------------------------------------------------------
__global__ __launch_bounds__(256) void graph_head_kernel(
    const float* __restrict__ g, const float* __restrict__ W2,
    const float* __restrict__ b2, const float* __restrict__ W3,
    const float* __restrict__ b3, float* __restrict__ out)
{
    const int i = blockIdx.x * 256 + threadIdx.x;
    if (i >= N_GRAPHS) return;

    float gv[D_H1];
    const float2* pg = (const float2*)(g + (size_t)i * D_H1);
#pragma unroll
    for (int j = 0; j < D_H1 / 2; ++j) {
        const float2 v = pg[j];
        gv[2*j] = v.x; gv[2*j+1] = v.y;
    }

    float h[D_H2];
#pragma unroll
    for (int tt = 0; tt < D_H2; ++tt) h[tt] = b2[tt];
#pragma unroll
    for (int j = 0; j < D_H1; ++j) {
#pragma unroll
        for (int tt = 0; tt < D_H2; ++tt) h[tt] = fmaf(gv[j], W2[j * D_H2 + tt], h[tt]);
    }

    float o = b3[0];
#pragma unroll
    for (int tt = 0; tt < D_H2; ++tt) o = fmaf(fmaxf(h[tt], 0.0f), W3[tt], o);

    out[i] = o;
}

// ---------------------------------------------------------------------------
extern "C" void kernel_launch(void* const* d_in, const int* in_sizes, int n_in,
                              void* d_out, int out_size, void* d_ws, size_t ws_size,
                              hipStream_t stream)
{
    (void)in_sizes; (void)n_in; (void)out_size; (void)ws_size;

    const int*   edge_index = (const int*)  d_in[0];
    const float* node_attr  = (const float*)d_in[1];
    const float* edge_attr  = (const float*)d_in[2];
    const int*   batch      = (const int*)  d_in[3];
    const float* W_msg      = (const float*)d_in[4];
    const float* b_msg      = (const float*)d_in[5];
    const float* W1         = (const float*)d_in[6];
    const float* b1         = (const float*)d_in[7];
    const float* W2         = (const float*)d_in[8];
    const float* b2         = (const float*)d_in[9];
    const float* W3         = (const float*)d_in[10];
    const float* b3         = (const float*)d_in[11];

    // ws: P[N_NODES*64] | g[20000] | cnt[100004] | offs[100004] | cur[100004]
    //     | bsum[128] | rec[N_EDGES int2]
    float* P    = (float*)d_ws;
    float* g    = P + (size_t)N_NODES * P_STRIDE;
    int*   cnt  = (int*)(g + (size_t)N_GRAPHS * D_H1);
    int*   offs = cnt + N_SCAN_PAD;
    int*   cur  = offs + N_SCAN_PAD;
    int*   bsum = cur + N_SCAN_PAD;
    int2*  rec  = (int2*)(bsum + 128);

    // zero g + cnt (adjacent)
    hipMemsetAsync(g, 0, ((size_t)N_GRAPHS * D_H1 + N_SCAN_PAD) * 4, stream);

    node_proj_hist_kernel<<<NB_EDGE, 256, 0, stream>>>(
        edge_index, node_attr, W_msg, b_msg, P, cnt);

    scan_a<<<NB_SCAN, 1024, 0, stream>>>(cnt, offs, bsum);
    scan_b<<<1, 128, 0, stream>>>(bsum);
    scan_c<<<NB_SCAN, 1024, 0, stream>>>(offs, bsum, cur);

    scatter_rec<<<NB_EDGE, 256, 0, stream>>>(edge_index, cur, rec);

    fused_edge_reduce_head<<<N_NODES / 32, 256, 0, stream>>>(
        rec, offs, P, edge_attr, W_msg, batch, W1, b1, g);

    graph_head_kernel<<<(N_GRAPHS + 255) / 256, 256, 0, stream>>>(
        g, W2, b2, W3, b3, (float*)d_out);
}

// Round 7
// 590.073 us; speedup vs baseline: 1.0603x; 1.0603x over previous
//
#include <hip/hip_runtime.h>

#define N_NODES    100000
#define N_EDGES    1600000
#define D_FEAT     64
#define N_GRAPHS   1000
#define D_MSG      30
#define D_H1       20
#define D_H2       10
#define P_STRIDE   64     // P row: [0..29]=P0(src proj + bias), pad, [32..61]=P1(dst proj), pad
#define N_SCAN     (N_NODES + 1)
#define N_SCAN_PAD 100004
#define NB_SCAN    ((N_SCAN + 1023) / 1024)   // 98
#define NB_EDGE    (N_EDGES / 256)            // 6250
#define NB_NODE    ((N_NODES + 255) / 256)    // 391

// native clang vector types (nontemporal builtins reject HIP_vector_type)
typedef float nfloat4 __attribute__((ext_vector_type(4)));
typedef int   nint2   __attribute__((ext_vector_type(2)));

// ---------------------------------------------------------------------------
// K0: merged  (a) histogram of dst over all 6250 blocks
//             (b) per-node projections P0/P1 on the first 391 blocks
// W0|W1 (rows 0..127 of W_msg) staged in LDS stride-32 -> uniform broadcasts.
// ---------------------------------------------------------------------------
__global__ __launch_bounds__(256, 4) void node_proj_hist_kernel(
    const int*   __restrict__ edge_index,  // [2][N_EDGES]
    const float* __restrict__ node_attr,   // [N_NODES][64]
    const float* __restrict__ W_msg,       // [192][30]
    const float* __restrict__ b_msg,       // [30]
    float*       __restrict__ P,           // [N_NODES][P_STRIDE]
    int*         __restrict__ cnt)         // [N_NODES] (pre-zeroed)
{
    const int t   = threadIdx.x;
    const int bid = blockIdx.x;

    // (a) histogram: every block covers 256 edges
    {
        const int e = bid * 256 + t;
        atomicAdd(&cnt[edge_index[N_EDGES + e]], 1);
    }

    if (bid >= NB_NODE) return;

    // (b) node projection
    __shared__ float wlds[128 * 32];
#pragma unroll
    for (int i = 0; i < 16; ++i) {
        const int f = t + i * 256;          // 0..4095
        const int k = f >> 5, j = f & 31;
        wlds[f] = (j < D_MSG) ? W_msg[k * D_MSG + j] : 0.0f;
    }
    __syncthreads();

    const int n = bid * 256 + t;
    if (n >= N_NODES) return;

    float a0[32], a1[32];
#pragma unroll
    for (int j = 0; j < 32; ++j) { a0[j] = 0.0f; a1[j] = 0.0f; }

    const float4* px = (const float4*)(node_attr + (size_t)n * D_FEAT);
#pragma unroll 4
    for (int q = 0; q < 16; ++q) {
        const float4 v = px[q];
        const float ev[4] = { v.x, v.y, v.z, v.w };
#pragma unroll
        for (int r = 0; r < 4; ++r) {
            const int k = 4 * q + r;
            const float4* w0 = (const float4*)&wlds[k * 32];
            const float4* w1 = (const float4*)&wlds[(64 + k) * 32];
#pragma unroll
            for (int jq = 0; jq < 8; ++jq) {
                const float4 w0v = w0[jq];
                const float4 w1v = w1[jq];
                a0[4*jq+0] = fmaf(ev[r], w0v.x, a0[4*jq+0]);
                a0[4*jq+1] = fmaf(ev[r], w0v.y, a0[4*jq+1]);
                a0[4*jq+2] = fmaf(ev[r], w0v.z, a0[4*jq+2]);
                a0[4*jq+3] = fmaf(ev[r], w0v.w, a0[4*jq+3]);
                a1[4*jq+0] = fmaf(ev[r], w1v.x, a1[4*jq+0]);
                a1[4*jq+1] = fmaf(ev[r], w1v.y, a1[4*jq+1]);
                a1[4*jq+2] = fmaf(ev[r], w1v.z, a1[4*jq+2]);
                a1[4*jq+3] = fmaf(ev[r], w1v.w, a1[4*jq+3]);
            }
        }
    }

    float4* pr = (float4*)(P + (size_t)n * P_STRIDE);
#pragma unroll
    for (int q = 0; q < 7; ++q)
        pr[q] = make_float4(a0[4*q] + b_msg[4*q], a0[4*q+1] + b_msg[4*q+1],
                            a0[4*q+2] + b_msg[4*q+2], a0[4*q+3] + b_msg[4*q+3]);
    pr[7] = make_float4(a0[28] + b_msg[28], a0[29] + b_msg[29], 0.0f, 0.0f);
#pragma unroll
    for (int q = 0; q < 7; ++q)
        pr[8 + q] = make_float4(a1[4*q], a1[4*q+1], a1[4*q+2], a1[4*q+3]);
    pr[15] = make_float4(a1[28], a1[29], 0.0f, 0.0f);
}

// ---------------------------------------------------------------------------
// CSR scan: 2-level exclusive scan of cnt -> offs, cursor init.
// ---------------------------------------------------------------------------
__global__ __launch_bounds__(1024) void scan_a(
    const int* __restrict__ cnt, int* __restrict__ offs, int* __restrict__ bsum)
{
    __shared__ int sh[1024];
    const int t = threadIdx.x;
    const int i = blockIdx.x * 1024 + t;
    const int v = (i < N_SCAN) ? cnt[i] : 0;
    sh[t] = v;
    __syncthreads();
#pragma unroll
    for (int off = 1; off < 1024; off <<= 1) {
        int u = 0;
        if (t >= off) u = sh[t - off];
        __syncthreads();
        if (t >= off) sh[t] += u;
        __syncthreads();
    }
    if (i < N_SCAN) offs[i] = sh[t] - v;
    if (t == 1023) bsum[blockIdx.x] = sh[1023];
}

__global__ __launch_bounds__(128) void scan_b(int* __restrict__ bsum)
{
    __shared__ int sh[128];
    const int t = threadIdx.x;
    const int v = (t < NB_SCAN) ? bsum[t] : 0;
    sh[t] = v;
    __syncthreads();
#pragma unroll
    for (int off = 1; off < 128; off <<= 1) {
        int u = 0;
        if (t >= off) u = sh[t - off];
        __syncthreads();
        if (t >= off) sh[t] += u;
        __syncthreads();
    }
    if (t < NB_SCAN) bsum[t] = sh[t] - v;
}

__global__ __launch_bounds__(1024) void scan_c(
    int* __restrict__ offs, const int* __restrict__ bsum, int* __restrict__ cur)
{
    const int i = blockIdx.x * 1024 + threadIdx.x;
    if (i < N_SCAN) {
        const int o = offs[i] + bsum[blockIdx.x];
        offs[i] = o;
        cur[i]  = o;
    }
}

// ---------------------------------------------------------------------------
// K4: scatter slot records (edge_id, src) into dst-sorted CSR order. 8B/edge.
// ---------------------------------------------------------------------------
__global__ __launch_bounds__(256) void scatter_rec(
    const int* __restrict__ edge_index, int* __restrict__ cur,
    int2* __restrict__ rec)
{
    const int e = blockIdx.x * 256 + threadIdx.x;
    const int s = edge_index[e];
    const int d = edge_index[N_EDGES + e];
    const int p = atomicAdd(&cur[d], 1);
    rec[p] = make_int2(e, s);
}

// ---------------------------------------------------------------------------
// K5: FUSED per-node kernel. 8 lanes per node (8 nodes/wave, 32 nodes/block).
//   m = P0[src] + P1[n] + e_attr[e] @ W2 ; acc += relu(m)   (registers only)
// 3-step shfl_xor butterfly -> node sum -> 30->20 head -> atomic pool into g.
// rec prefetched one slot ahead. e_attr/rec loads are nontemporal (read-once
// streams) so the P table stays resident in L2/L3 for the random gathers.
// __launch_bounds__(256,4): natural VGPR alloc (~64), NO forced cap (R5's
// (256,8) forced VGPR=32 and spilled m[] to scratch: +450MB FETCH, 1.3x slower).
// ---------------------------------------------------------------------------
__global__ __launch_bounds__(256, 4) void fused_edge_reduce_head(
    const int*   __restrict__ rec,         // [N_EDGES][2] (e, src) dst-sorted
    const int*   __restrict__ offs,        // [N_NODES+1]
    const float* __restrict__ P,           // [N_NODES][P_STRIDE]
    const float* __restrict__ edge_attr,   // [N_EDGES][64]
    const float* __restrict__ W_msg,       // rows 128..191 = W2
    const int*   __restrict__ batch,       // [N_NODES]
    const float* __restrict__ W1,          // [30][20]
    const float* __restrict__ b1,          // [20]
    float*       __restrict__ g)           // [N_GRAPHS][20] (pre-zeroed)
{
    __shared__ float wlds[64 * 32];
    const int t = threadIdx.x;
#pragma unroll
    for (int i = 0; i < 8; ++i) {
        const int f = t + i * 256;          // 0..2047
        const int k = f >> 5, j = f & 31;
        wlds[f] = (j < D_MSG) ? W_msg[(2 * D_FEAT + k) * D_MSG + j] : 0.0f;
    }
    __syncthreads();

    const int lane = t & 63;
    const int l8   = lane & 7;
    const int grp  = lane >> 3;                       // 0..7
    const int wid  = t >> 6;                          // 0..3
    const int n    = blockIdx.x * 32 + wid * 8 + grp; // grid covers exactly N_NODES

    const int o0 = offs[n], o1 = offs[n + 1];
    const float4* p1 = (const float4*)(P + (size_t)n * P_STRIDE + 32);

    float acc[30];
#pragma unroll
    for (int j = 0; j < 30; ++j) acc[j] = 0.0f;

    int   o = o0 + l8;
    nint2 r = {0, 0};
    if (o < o1) r = __builtin_nontemporal_load((const nint2*)(rec + 2 * (size_t)o));
    while (o < o1) {
        const int e = r.x, s = r.y;
        const int on = o + 8;
        if (on < o1)
            r = __builtin_nontemporal_load((const nint2*)(rec + 2 * (size_t)on)); // prefetch

        const float4*  p0 = (const float4*)(P + (size_t)s * P_STRIDE);
        const nfloat4* pe = (const nfloat4*)(edge_attr + (size_t)e * D_FEAT);

        float m[32];
#pragma unroll
        for (int q = 0; q < 8; ++q) {
            const float4 u = p0[q];
            const float4 w = p1[q];
            m[4*q+0] = u.x + w.x; m[4*q+1] = u.y + w.y;
            m[4*q+2] = u.z + w.z; m[4*q+3] = u.w + w.w;
        }
#pragma unroll 4
        for (int q = 0; q < 16; ++q) {
            const nfloat4 v = __builtin_nontemporal_load(pe + q);
            const float ev[4] = { v.x, v.y, v.z, v.w };
#pragma unroll
            for (int rr = 0; rr < 4; ++rr) {
                const float4* wr = (const float4*)&wlds[(4 * q + rr) * 32];
#pragma unroll
                for (int jq = 0; jq < 8; ++jq) {
                    const float4 wv = wr[jq];
                    m[4*jq+0] = fmaf(ev[rr], wv.x, m[4*jq+0]);
                    m[4*jq+1] = fmaf(ev[rr], wv.y, m[4*jq+1]);
                    m[4*jq+2] = fmaf(ev[rr], wv.z, m[4*jq+2]);
                    m[4*jq+3] = fmaf(ev[rr], wv.w, m[4*jq+3]);
                }
            }
        }
#pragma unroll
        for (int j = 0; j < 30; ++j) acc[j] += fmaxf(m[j], 0.0f);
        o = on;
    }

    // 8-lane butterfly: all 8 lanes of the group end with the full node sum
#pragma unroll
    for (int off = 1; off < 8; off <<= 1) {
#pragma unroll
        for (int j = 0; j < 30; ++j)
            acc[j] += __shfl_xor(acc[j], off, 8);
    }

    // head: columns l8, l8+8 on each lane; columns 16..19 on lanes 0..3
    const int gi = batch[n];
    {
        float h = b1[l8];
#pragma unroll
        for (int j = 0; j < 30; ++j) h = fmaf(acc[j], W1[j * D_H1 + l8], h);
        h = fmaxf(h, 0.0f);
        if (h > 0.0f) atomicAdd(&g[(size_t)gi * D_H1 + l8], h);
    }
    {
        const int c = 8 + l8;
        float h = b1[c];
#pragma unroll
        for (int j = 0; j < 30; ++j) h = fmaf(acc[j], W1[j * D_H1 + c], h);
        h = fmaxf(h, 0.0f);
        if (h > 0.0f) atomicAdd(&g[(size_t)gi * D_H1 + c], h);
    }
    if (l8 < 4) {
        const int c = 16 + l8;
        float h = b1[c];
#pragma unroll
        for (int j = 0; j < 30; ++j) h = fmaf(acc[j], W1[j * D_H1 + c], h);
        h = fmaxf(h, 0.0f);
        if (h > 0.0f) atomicAdd(&g[(size_t)gi * D_H1 + c], h);
    }
}

// ---------------------------------------------------------------------------
// K6: per-graph head  out = relu(g @ W2 + b2) @ W3 + b3
// ---------------------------------------------------------------------------
__global__ __launch_bounds__(256) void graph_head_kernel(
    const float* __restrict__ g, const float* __restrict__ W2,
    const float* __restrict__ b2, const float* __restrict__ W3,
    const float* __restrict__ b3, float* __restrict__ out)
{
    const int i = blockIdx.x * 256 + threadIdx.x;
    if (i >= N_GRAPHS) return;

    float gv[D_H1];
    const float2* pg = (const float2*)(g + (size_t)i * D_H1);
#pragma unroll
    for (int j = 0; j < D_H1 / 2; ++j) {
        const float2 v = pg[j];
        gv[2*j] = v.x; gv[2*j+1] = v.y;
    }

    float h[D_H2];
#pragma unroll
    for (int tt = 0; tt < D_H2; ++tt) h[tt] = b2[tt];
#pragma unroll
    for (int j = 0; j < D_H1; ++j) {
#pragma unroll
        for (int tt = 0; tt < D_H2; ++tt) h[tt] = fmaf(gv[j], W2[j * D_H2 + tt], h[tt]);
    }

    float o = b3[0];
#pragma unroll
    for (int tt = 0; tt < D_H2; ++tt) o = fmaf(fmaxf(h[tt], 0.0f), W3[tt], o);

    out[i] = o;
}

// ---------------------------------------------------------------------------
extern "C" void kernel_launch(void* const* d_in, const int* in_sizes, int n_in,
                              void* d_out, int out_size, void* d_ws, size_t ws_size,
                              hipStream_t stream)
{
    (void)in_sizes; (void)n_in; (void)out_size; (void)ws_size;

    const int*   edge_index = (const int*)  d_in[0];
    const float* node_attr  = (const float*)d_in[1];
    const float* edge_attr  = (const float*)d_in[2];
    const int*   batch      = (const int*)  d_in[3];
    const float* W_msg      = (const float*)d_in[4];
    const float* b_msg      = (const float*)d_in[5];
    const float* W1         = (const float*)d_in[6];
    const float* b1         = (const float*)d_in[7];
    const float* W2         = (const float*)d_in[8];
    const float* b2         = (const float*)d_in[9];
    const float* W3         = (const float*)d_in[10];
    const float* b3         = (const float*)d_in[11];

    // ws: P[N_NODES*64] | g[20000] | cnt[100004] | offs[100004] | cur[100004]
    //     | bsum[128] | rec[N_EDGES int2]
    float* P    = (float*)d_ws;
    float* g    = P + (size_t)N_NODES * P_STRIDE;
    int*   cnt  = (int*)(g + (size_t)N_GRAPHS * D_H1);
    int*   offs = cnt + N_SCAN_PAD;
    int*   cur  = offs + N_SCAN_PAD;
    int*   bsum = cur + N_SCAN_PAD;
    int2*  rec  = (int2*)(bsum + 128);

    // zero g + cnt (adjacent)
    (void)hipMemsetAsync(g, 0, ((size_t)N_GRAPHS * D_H1 + N_SCAN_PAD) * 4, stream);

    node_proj_hist_kernel<<<NB_EDGE, 256, 0, stream>>>(
        edge_index, node_attr, W_msg, b_msg, P, cnt);

    scan_a<<<NB_SCAN, 1024, 0, stream>>>(cnt, offs, bsum);
    scan_b<<<1, 128, 0, stream>>>(bsum);
    scan_c<<<NB_SCAN, 1024, 0, stream>>>(offs, bsum, cur);

    scatter_rec<<<NB_EDGE, 256, 0, stream>>>(edge_index, cur, rec);

    fused_edge_reduce_head<<<N_NODES / 32, 256, 0, stream>>>(
        (const int*)rec, offs, P, edge_attr, W_msg, batch, W1, b1, g);

    graph_head_kernel<<<(N_GRAPHS + 255) / 256, 256, 0, stream>>>(
        g, W2, b2, W3, b3, (float*)d_out);
}